// Round 8
// baseline (143.479 us; speedup 1.0000x reference)
//
#include <hip/hip_runtime.h>

#define NB     64
#define NOBJ   50
#define ND     8732
#define BLK    256
#define NW     (BLK/64)              // 4 waves
#define PPT    4
#define PRB    (BLK*PPT)             // 1024 priors per per-prior block
#define NBA    9                     // ceil(8732/1024); last split = 540 (540%4==0)
#define TB     13                    // per-truth blocks per batch (4 truths each, 52>=50)
#define GRID   (NB*NBA + NB*TB)      // 576 + 832 = 1408
#define TILE   1024                  // priors per LDS tile in per-truth path
#define NTILE  ((ND + TILE - 1)/TILE)
#define BLK2   1024
#define NW2    (BLK2/64)
#define ITER2  ((ND+BLK2-1)/BLK2)    // 9
#define ND4    (ND/4)                // 2183

// device scratch — every element rewritten each launch (graph-replay safe, deterministic)
__device__ float              g_part[NB*5];
__device__ float4             g_ce4[(size_t)NB*ND4];     // signed ce_mined (pos -> -ce_pos)
__device__ unsigned long long g_keys[NB*NOBJ];           // FINAL per-truth keys
__device__ int                g_hist[(size_t)NB*NBA*256];
__device__ float              g_bp[NB*NBA*3];            // per-split npos/sl1/scep
__device__ int                g_done;

// bit-exact IoU (used identically in per-prior, per-truth, and k2-correction paths)
__device__ __forceinline__ float iou_rn(float px1,float py1,float px2,float py2,float pa,
                                        float tx1,float ty1,float tx2,float ty2,float ta){
    float ltx=fmaxf(tx1,px1), lty=fmaxf(ty1,py1);
    float rbx=fminf(tx2,px2), rby=fminf(ty2,py2);
    float ww=fmaxf(__fsub_rn(rbx,ltx),0.f), hh=fmaxf(__fsub_rn(rby,lty),0.f);
    float inter=__fmul_rn(ww,hh);
    return __fdividef(inter, __fsub_rn(__fadd_rn(ta,pa),inter));
}
__device__ __forceinline__ float lse2(float x0,float x1){
    float m=fmaxf(x0,x1);
    return m+__logf(__expf(x0-m)+__expf(x1-m));
}
__device__ __forceinline__ float sl1_enc(float4 p,float tx1,float ty1,float tx2,float ty2,float4 ld){
    float g0=((tx1+tx2)*0.5f-p.x)/(0.1f*p.z);
    float g1=((ty1+ty2)*0.5f-p.y)/(0.1f*p.w);
    float g2=__logf((tx2-tx1)/p.z)*5.0f;
    float g3=__logf((ty2-ty1)/p.w)*5.0f;
    float t0=fabsf(ld.x-g0),t1=fabsf(ld.y-g1),t2=fabsf(ld.z-g2),t3=fabsf(ld.w-g3);
    return (t0<1.f?0.5f*t0*t0:t0-0.5f)+(t1<1.f?0.5f*t1*t1:t1-0.5f)
          +(t2<1.f?0.5f*t2*t2:t2-0.5f)+(t3<1.f?0.5f*t3*t3:t3-0.5f);
}

// ---------------- K1 fused grid: per-prior blocks + per-truth blocks ----------------
__global__ __launch_bounds__(BLK) void k1(const float* __restrict__ loc_data,
                                          const float* __restrict__ conf_data,
                                          const float* __restrict__ dbox,
                                          const float* __restrict__ targets){
    // per-prior path LDS
    __shared__ float s_tx1[NOBJ],s_ty1[NOBJ],s_tx2[NOBJ],s_ty2[NOBJ],s_lab[NOBJ];
    __shared__ int   s_wh[NW*256];
    __shared__ float s_r1[NW],s_r2[NW],s_r3[NW];
    // per-truth path LDS (SoA prior tile)
    __shared__ float s_px1[TILE],s_py1[TILE],s_px2[TILE],s_py2[TILE],s_pa[TILE];

    const int blk=blockIdx.x, tid=threadIdx.x, lane=tid&63, wv=tid>>6;
    const float4* dbox4=reinterpret_cast<const float4*>(dbox);
    if (blk==0 && tid==0) g_done=0;

    if (blk < NB*NBA) {
        // ============ per-prior path ============
        const int b=blk/NBA, spl=blk%NBA;
        if (tid<NOBJ){
            const float* t=targets+(b*NOBJ+tid)*5;
            s_tx1[tid]=t[0];s_ty1[tid]=t[1];s_tx2[tid]=t[2];s_ty2[tid]=t[3];s_lab[tid]=t[4];
        }
        for (int i=tid;i<NW*256;i+=BLK) s_wh[i]=0;
        __syncthreads();

        const int d0=spl*PRB;
        const bool vld=(d0+tid*PPT)<ND;      // split size always %4==0
        float px1[PPT],py1[PPT],px2[PPT],py2[PPT],pa[PPT];
        float bov[PPT]; int bj[PPT];
#pragma unroll
        for (int q=0;q<PPT;++q){
            bov[q]=-1.f; bj[q]=0;
            px1[q]=py1[q]=px2[q]=py2[q]=pa[q]=0.f;
            if (vld){
                float4 p=dbox4[d0+tid*PPT+q];
                float hw=__fmul_rn(0.5f,p.z), hh=__fmul_rn(0.5f,p.w);
                px1[q]=__fsub_rn(p.x,hw); py1[q]=__fsub_rn(p.y,hh);
                px2[q]=__fadd_rn(p.x,hw); py2[q]=__fadd_rn(p.y,hh);
                pa[q]=__fmul_rn(p.z,p.w);
            }
        }
        // match loop: truths via uniform scalar loads (SGPR), NO cross-lane ops
        const float* tg=targets+(size_t)b*NOBJ*5;
        for (int c=0;c<5;++c){
            float tx1c[10],ty1c[10],tx2c[10],ty2c[10],tac[10];
#pragma unroll
            for (int jj=0;jj<10;++jj){
                int j=c*10+jj;
                tx1c[jj]=tg[j*5+0]; ty1c[jj]=tg[j*5+1];
                tx2c[jj]=tg[j*5+2]; ty2c[jj]=tg[j*5+3];
                tac[jj]=__fmul_rn(__fsub_rn(tx2c[jj],tx1c[jj]),__fsub_rn(ty2c[jj],ty1c[jj]));
            }
#pragma unroll
            for (int q=0;q<PPT;++q){
#pragma unroll
                for (int jj=0;jj<10;++jj){
                    float iou=iou_rn(px1[q],py1[q],px2[q],py2[q],pa[q],
                                     tx1c[jj],ty1c[jj],tx2c[jj],ty2c[jj],tac[jj]);
                    if (iou>bov[q]){bov[q]=iou;bj[q]=c*10+jj;}   // first-max (smallest j)
                }
            }
        }
        // CE/L1 phase (no-override view): signed ce_mined + histogram
        float np=0.f,sl=0.f,sc=0.f;
        if (vld){
            const size_t cbase=((size_t)b*ND+d0)/2;
            float4 cfa=reinterpret_cast<const float4*>(conf_data)[cbase+tid*2];
            float4 cfb=reinterpret_cast<const float4*>(conf_data)[cbase+tid*2+1];
            float raw[PPT];
#pragma unroll
            for (int q=0;q<PPT;++q){
                const int d=d0+tid*PPT+q;
                float cfx=(q==0)?cfa.x:(q==1)?cfa.z:(q==2)?cfb.x:cfb.z;
                float cfy=(q==0)?cfa.y:(q==1)?cfa.w:(q==2)?cfb.y:cfb.w;
                float l=lse2(cfx,cfy);
                bool pos=!(bov[q]<0.5f);
                int jb=bj[q];
                int lab=pos?((int)s_lab[jb]+1):0;
                float cev=l-(lab>=1?cfy:cfx);
                raw[q]=pos?-cev:cev;
                atomicAdd(&s_wh[wv*256+(int)(__float_as_uint(fmaxf(raw[q],0.f))>>24)],1);
                if (pos){
                    np+=1.f; sc+=cev;
                    float4 p=dbox4[d];
                    float4 ldv=reinterpret_cast<const float4*>(loc_data)[(size_t)b*ND+d];
                    sl+=sl1_enc(p,s_tx1[jb],s_ty1[jb],s_tx2[jb],s_ty2[jb],ldv);
                }
            }
            float4 st; st.x=raw[0];st.y=raw[1];st.z=raw[2];st.w=raw[3];
            g_ce4[((size_t)b*ND+d0)/4+tid]=st;
        }
#pragma unroll
        for (int off=32;off>=1;off>>=1){
            np+=__shfl_xor(np,off,64); sl+=__shfl_xor(sl,off,64); sc+=__shfl_xor(sc,off,64);
        }
        if (lane==0){s_r1[wv]=np;s_r2[wv]=sl;s_r3[wv]=sc;}
        __syncthreads();
        if (tid==0){
            float a=0.f,bb=0.f,cc=0.f;
            for (int w=0;w<NW;++w){a+=s_r1[w];bb+=s_r2[w];cc+=s_r3[w];}
            g_bp[(b*NBA+spl)*3+0]=a;
            g_bp[(b*NBA+spl)*3+1]=bb;
            g_bp[(b*NBA+spl)*3+2]=cc;
        }
        if (tid<256){
            int s=0;
            for (int w=0;w<NW;++w) s+=s_wh[w*256+tid];
            g_hist[(size_t)(b*NBA+spl)*256+tid]=s;
        }
    } else {
        // ============ per-truth path: one wave = one truth, LDS-staged priors ============
        const int r=blk-NB*NBA;
        const int b=r/TB;
        const int t=(r%TB)*NW+wv;
        const bool tv=t<NOBJ;
        float tx1=0,ty1=0,tx2=0,ty2=0,ta=1.f;
        if (tv){
            const float* tt=targets+(b*NOBJ+t)*5;
            tx1=tt[0];ty1=tt[1];tx2=tt[2];ty2=tt[3];
            ta=__fmul_rn(__fsub_rn(tx2,tx1),__fsub_rn(ty2,ty1));
        }
        float bt=-1.f; int bd=0;
        for (int tile=0;tile<NTILE;++tile){
            const int base=tile*TILE;
#pragma unroll
            for (int i=0;i<TILE/BLK;++i){
                int dl=tid+i*BLK;
                int d=base+dl;
                float4 p=make_float4(0.f,0.f,0.f,0.f);
                if (d<ND) p=dbox4[d];
                float hw=__fmul_rn(0.5f,p.z), hh=__fmul_rn(0.5f,p.w);
                s_px1[dl]=__fsub_rn(p.x,hw); s_py1[dl]=__fsub_rn(p.y,hh);
                s_px2[dl]=__fadd_rn(p.x,hw); s_py2[dl]=__fadd_rn(p.y,hh);
                s_pa[dl]=__fmul_rn(p.z,p.w);
            }
            __syncthreads();
            if (tv){
#pragma unroll 4
                for (int dd=lane;dd<TILE;dd+=64){
                    float iou=iou_rn(s_px1[dd],s_py1[dd],s_px2[dd],s_py2[dd],s_pa[dd],
                                     tx1,ty1,tx2,ty2,ta);
                    if (iou>bt){bt=iou;bd=base+dd;}   // in-lane ascending d: keeps smallest d
                }
            }
            __syncthreads();
        }
        if (tv){
            // exact first-max across lanes via u64 (iou<<32)|~d max
            unsigned long long key=((unsigned long long)__float_as_uint(bt)<<32)
                                  |(unsigned long long)(0xFFFFFFFFu-(unsigned)bd);
#pragma unroll
            for (int off=32;off>=1;off>>=1){
                unsigned long long o=__shfl_xor(key,off,64);
                if (o>key) key=o;
            }
            if (lane==0) g_keys[b*NOBJ+t]=key;
        }
    }
}

// ---------------- K2: corrections + radix select + fused finisher ----------------
__global__ __launch_bounds__(BLK2) void k2(const float* __restrict__ loc_data,
                                           const float* __restrict__ conf_data,
                                           const float* __restrict__ dbox,
                                           const float* __restrict__ targets,
                                           float* __restrict__ out){
    __shared__ float4 s_ce4[ND4];
    __shared__ unsigned int s_dj[NOBJ];
    __shared__ float s_tx1[NOBJ],s_ty1[NOBJ],s_tx2[NOBJ],s_ty2[NOBJ],s_ta[NOBJ],s_lab[NOBJ];
    __shared__ int   s_hist[256];
    __shared__ int   s_wh[NW2*256];
    __shared__ float s_bpl[NBA*3];
    __shared__ float s_rf[NW2]; __shared__ int s_ri[NW2];
    __shared__ int   s_wt[4];
    __shared__ float s_dnp,s_dsl,s_dsc;
    __shared__ int   s_sel,s_krem,s_kk,s_last;
    float* s_ce=(float*)s_ce4;

    const int b=blockIdx.x, tid=threadIdx.x, lane=tid&63, wv=tid>>6;

    if (tid<NOBJ){
        const float* t=targets+(b*NOBJ+tid)*5;
        float x1=t[0],y1=t[1],x2=t[2],y2=t[3];
        s_tx1[tid]=x1;s_ty1[tid]=y1;s_tx2[tid]=x2;s_ty2[tid]=y2;
        s_ta[tid]=__fmul_rn(__fsub_rn(x2,x1),__fsub_rn(y2,y1));
        s_lab[tid]=t[4];
        s_dj[tid]=0xFFFFFFFFu-(unsigned)(g_keys[b*NOBJ+tid]&0xFFFFFFFFull);
    }
    for (int i=tid;i<ND4;i+=BLK2) s_ce4[i]=g_ce4[(size_t)b*ND4+i];
    if (tid<256){
        int s=0;
        for (int sp=0;sp<NBA;++sp) s+=g_hist[(size_t)(b*NBA+sp)*256+tid];
        s_hist[tid]=s;
    }
    if (tid<NBA*3) s_bpl[tid]=g_bp[b*NBA*3+tid];
    __syncthreads();

    // override corrections (<=50 priors forced positive, last-write-wins)
    float dnp=0.f,dsl=0.f,dsc=0.f;
    if (tid<NOBJ){
        unsigned d=s_dj[tid]; bool win=true;
        for (int j2=tid+1;j2<NOBJ;++j2) if (s_dj[j2]==d){win=false;break;}
        if (win){
            float4 p=reinterpret_cast<const float4*>(dbox)[d];
            float hw=__fmul_rn(0.5f,p.z), hh2=__fmul_rn(0.5f,p.w);
            float ppx1=__fsub_rn(p.x,hw),ppy1=__fsub_rn(p.y,hh2);
            float ppx2=__fadd_rn(p.x,hw),ppy2=__fadd_rn(p.y,hh2);
            float ppa=__fmul_rn(p.z,p.w);
            float bov=-1.f; int jb=0;
            for (int j=0;j<NOBJ;++j){     // bit-identical recompute of per-prior match
                float iou=iou_rn(ppx1,ppy1,ppx2,ppy2,ppa,
                                 s_tx1[j],s_ty1[j],s_tx2[j],s_ty2[j],s_ta[j]);
                if (iou>bov){bov=iou;jb=j;}
            }
            bool oldpos=!(bov<0.5f);
            float2 cf=reinterpret_cast<const float2*>(conf_data)[(size_t)b*ND+d];
            float l=lse2(cf.x,cf.y);
            float4 ldv=reinterpret_cast<const float4*>(loc_data)[(size_t)b*ND+d];
            int labN=(int)s_lab[tid]+1;
            float ceN=l-(labN>=1?cf.y:cf.x);
            dsc+=ceN; dsl+=sl1_enc(p,s_tx1[tid],s_ty1[tid],s_tx2[tid],s_ty2[tid],ldv);
            if (oldpos){
                int labO=(int)s_lab[jb]+1;
                float ceO=l-(labO>=1?cf.y:cf.x);
                dsc-=ceO; dsl-=sl1_enc(p,s_tx1[jb],s_ty1[jb],s_tx2[jb],s_ty2[jb],ldv);
            } else dnp+=1.f;
            float oldraw=s_ce[d];
            atomicAdd(&s_hist[(int)(__float_as_uint(fmaxf(oldraw,0.f))>>24)],-1);
            atomicAdd(&s_hist[0],1);
            s_ce[d]=-ceN;
        }
    }
    if (wv==0){
#pragma unroll
        for (int off=32;off>=1;off>>=1){
            dnp+=__shfl_xor(dnp,off,64); dsl+=__shfl_xor(dsl,off,64); dsc+=__shfl_xor(dsc,off,64);
        }
        if (lane==0){s_dnp=dnp;s_dsl=dsl;s_dsc=dsc;}
    }
    __syncthreads();
    if (tid==0){
        float np=s_dnp, sl=s_dsl, sc=s_dsc;
        for (int i=0;i<NBA;++i){np+=s_bpl[i*3];sl+=s_bpl[i*3+1];sc+=s_bpl[i*3+2];}
        int npi=(int)np; int k=npi*3; if(k<20)k=20; if(k>ND)k=ND;
        s_kk=k;
        g_part[b*5+0]=np; g_part[b*5+1]=sl; g_part[b*5+2]=sc; g_part[b*5+3]=(float)k;
    }
    __syncthreads();
    const int k=s_kk;

    // radix select: pass 1 free from histogram; passes 2-3 scan LDS
    unsigned prefix=0u,pmask=0u; int krem=k;
    for (int p=0;p<3;++p){
        const int shift=24-p*8;
        int cnt=0;
        if (p==0){
            if (tid<256) cnt=s_hist[tid];
        } else {
            for (int i=tid;i<NW2*256;i+=BLK2) s_wh[i]=0;
            __syncthreads();
            for (int it=0;it<ITER2;++it){
                int d=tid+it*BLK2;
                if (d<ND){
                    unsigned vb=__float_as_uint(fmaxf(s_ce[d],0.f));
                    if ((vb&pmask)==prefix)
                        atomicAdd(&s_wh[wv*256+(int)((vb>>shift)&255u)],1);
                }
            }
            __syncthreads();
            if (tid<256){
                for (int w=0;w<NW2;++w) cnt+=s_wh[w*256+tid];
            }
        }
        int S=cnt,add=0;
        if (tid<256){
#pragma unroll
            for (int off=1;off<64;off<<=1){
                int t=__shfl_down(S,off,64);
                if (lane+off<64) S+=t;
            }
            if (lane==0) s_wt[wv]=S;
        }
        __syncthreads();
        if (tid<256){
            for (int w=wv+1;w<4;++w) add+=s_wt[w];
            S+=add;
            int Snext=__shfl_down(S,1,64);
            if (lane==63) Snext=add;
            if (S>=krem && Snext<krem){s_sel=tid;s_krem=krem-(S-cnt);}
        }
        __syncthreads();
        prefix|=((unsigned)s_sel)<<shift;
        pmask|=255u<<shift;
        krem=s_krem;
        __syncthreads();
    }
    const float T=__uint_as_float(prefix);

    int cgt=0; float sgt=0.f;
    for (int it=0;it<ITER2;++it){
        int d=tid+it*BLK2;
        if (d<ND){
            float v=fmaxf(s_ce[d],0.f);
            if (v>T){cgt++;sgt+=v;}
        }
    }
#pragma unroll
    for (int off=32;off>=1;off>>=1){cgt+=__shfl_xor(cgt,off,64);sgt+=__shfl_xor(sgt,off,64);}
    if (lane==0){s_ri[wv]=cgt;s_rf[wv]=sgt;}
    __syncthreads();
    if (tid==0){
        int cg=0; float sg=0.f;
        for (int w=0;w<NW2;++w){cg+=s_ri[w];sg+=s_rf[w];}
        int need=k-cg;
        float stk=sg+(float)need*T;
        if (!(T>0.f)&&need>0){
            // T==0: stable index-order tie pool = {raw<=0}; original ce = |raw|
            int taken=0;
            for (int d=0;d<ND&&taken<need;++d){
                float r2=s_ce[d];
                if (!(r2>0.f)){stk+=fabsf(r2);++taken;}
            }
        }
        g_part[b*5+4]=stk;
    }

    if (tid==0){__threadfence(); int old=atomicAdd(&g_done,1); s_last=(old==NB-1)?1:0;}
    __syncthreads();
    if (s_last&&tid<NB){
        __threadfence();
        volatile float* gp=g_part;
        float np=gp[tid*5+0],sl=gp[tid*5+1],sc=gp[tid*5+2],kk=gp[tid*5+3],st=gp[tid*5+4];
#pragma unroll
        for (int off=32;off>=1;off>>=1){
            np+=__shfl_xor(np,off,64);sl+=__shfl_xor(sl,off,64);
            sc+=__shfl_xor(sc,off,64);kk+=__shfl_xor(kk,off,64);st+=__shfl_xor(st,off,64);
        }
        if (tid==0){
            float loss_l=(np>0.f)?sl/(4.f*np):0.f;
            float lcp=(np>0.f)?sc/np:0.f;
            float lcn=(kk>0.f)?st/kk:0.f;
            out[0]=loss_l;out[1]=lcp+lcn;out[2]=lcp;out[3]=lcn;
        }
    }
}

extern "C" void kernel_launch(void* const* d_in, const int* in_sizes, int n_in,
                              void* d_out, int out_size, void* d_ws, size_t ws_size,
                              hipStream_t stream) {
    const float* loc     = (const float*)d_in[0];
    const float* conf    = (const float*)d_in[1];
    const float* dboxp   = (const float*)d_in[2];
    const float* targets = (const float*)d_in[3];
    float* out = (float*)d_out;

    k1<<<GRID, BLK, 0, stream>>>(loc, conf, dboxp, targets);
    k2<<<NB, BLK2, 0, stream>>>(loc, conf, dboxp, targets, out);
}